// Round 2
// baseline (621.316 us; speedup 1.0000x reference)
//
#include <hip/hip_runtime.h>
#include <hip/hip_bf16.h>
#include <stdint.h>

#define BATCH 8192
#define KDIM  4096   // IN_FEATURES
#define NDIM  4096   // OUT_FEATURES

#define BM 128
#define BN 128
#define BK 32

typedef __bf16 bf16x8 __attribute__((ext_vector_type(8)));
typedef float  f32x4  __attribute__((ext_vector_type(4)));

__device__ inline float bf2f(uint32_t h) {
    union { uint32_t u; float f; } c; c.u = h << 16; return c.f;
}

// ---------------------------------------------------------------------------
// Kernel 0: detect dtypes device-side (graph-safe, deterministic).
// flags[0]: 1 if x is fp32, 0 if bf16
// flags[1]: 1 if w is fp32, 0 if bf16
// flags[2]: mask enc: 0=int32{0,1}, 1=uint8 bytes, 2=bf16 halves, 3=fp32 {0,1.0f}
// Detector: in a 32-bit word of bf16 pairs, the LOW half is a bf16 value whose
// exponent field (bits 14..7) concentrates in [0x70,0x86] for N(0,1) data
// (~100% of samples). For fp32 data those bits are mid-mantissa -> uniform
// (~9% hit rate). 4096 samples, threshold 2048: unambiguous.
// ---------------------------------------------------------------------------
__global__ void detect_kernel(const uint32_t* __restrict__ x,
                              const uint32_t* __restrict__ w,
                              const uint32_t* __restrict__ m,
                              int* __restrict__ flags) {
    __shared__ int cx, cw, all01, allf32, anybf16;
    if (threadIdx.x == 0) { cx = 0; cw = 0; all01 = 1; allf32 = 1; anybf16 = 0; }
    __syncthreads();
    int lcx = 0, lcw = 0, la01 = 1, laf = 1, lab = 0;
    for (int i = threadIdx.x; i < 4096; i += blockDim.x) {
        uint32_t vx = x[i], vw = w[i], vm = m[i];
        uint32_t ex = (vx >> 7) & 0xFFu; if (ex >= 0x70u && ex <= 0x86u) lcx++;
        uint32_t ew = (vw >> 7) & 0xFFu; if (ew >= 0x70u && ew <= 0x86u) lcw++;
        if (vm > 1u) la01 = 0;
        if (vm != 0u && vm != 0x3F800000u) laf = 0;
        if ((vm & 0xFFFFu) == 0x3F80u || (vm >> 16) == 0x3F80u) lab = 1;
    }
    atomicAdd(&cx, lcx); atomicAdd(&cw, lcw);
    if (!la01) atomicAnd(&all01, 0);
    if (!laf)  atomicAnd(&allf32, 0);
    if (lab)   atomicOr(&anybf16, 1);
    __syncthreads();
    if (threadIdx.x == 0) {
        flags[0] = (cx < 2048) ? 1 : 0;
        flags[1] = (cw < 2048) ? 1 : 0;
        int f;
        if (all01)        f = 0;
        else if (allf32)  f = 3;
        else if (anybf16) f = 2;
        else              f = 1;
        flags[2] = f;
    }
}

// ---------------------------------------------------------------------------
// Kernel 1 (fused prep): blocks [0,16384) convert x -> bf16 into xb (only if
// x is fp32); blocks [16384,24576) compute wm = bf16(w * mask).
// 8 elements per thread, 16-B stores.
// ---------------------------------------------------------------------------
__global__ void prep_kernel(const void* __restrict__ x,
                            const void* __restrict__ w,
                            const void* __restrict__ mask,
                            const int*  __restrict__ flags,
                            uint4* __restrict__ xb4,
                            uint4* __restrict__ wm4) {
    const int fx = flags[0], fw = flags[1], fm = flags[2];
    if (blockIdx.x < 16384) {
        // ---- x conversion job: 16384 blocks * 256 thr * 8 elems = 33.5M ----
        if (fx == 0) return;                       // x already bf16; gemm reads it directly
        const int t = blockIdx.x * 256 + threadIdx.x;
        const float4* xf = (const float4*)x;
        float4 a = xf[(size_t)t * 2], b = xf[(size_t)t * 2 + 1];
        union { __hip_bfloat16 h[8]; uint4 u; } o;
        o.h[0] = __float2bfloat16(a.x); o.h[1] = __float2bfloat16(a.y);
        o.h[2] = __float2bfloat16(a.z); o.h[3] = __float2bfloat16(a.w);
        o.h[4] = __float2bfloat16(b.x); o.h[5] = __float2bfloat16(b.y);
        o.h[6] = __float2bfloat16(b.z); o.h[7] = __float2bfloat16(b.w);
        xb4[t] = o.u;
    } else {
        // ---- w*mask job: 8192 blocks * 256 thr * 8 elems = 16.7M ----
        const int t = (blockIdx.x - 16384) * 256 + threadIdx.x;
        float wv[8];
        if (fw) {
            const float4* wf = (const float4*)w;
            float4 a = wf[(size_t)t * 2], b = wf[(size_t)t * 2 + 1];
            wv[0] = a.x; wv[1] = a.y; wv[2] = a.z; wv[3] = a.w;
            wv[4] = b.x; wv[5] = b.y; wv[6] = b.z; wv[7] = b.w;
        } else {
            uint4 wb = *((const uint4*)w + t);
            wv[0] = bf2f(wb.x & 0xFFFFu); wv[1] = bf2f(wb.x >> 16);
            wv[2] = bf2f(wb.y & 0xFFFFu); wv[3] = bf2f(wb.y >> 16);
            wv[4] = bf2f(wb.z & 0xFFFFu); wv[5] = bf2f(wb.z >> 16);
            wv[6] = bf2f(wb.w & 0xFFFFu); wv[7] = bf2f(wb.w >> 16);
        }
        int kb[8];
        if (fm == 1) {                 // uint8 bool bytes
            uint2 m2 = *((const uint2*)mask + t);
            #pragma unroll
            for (int j = 0; j < 4; ++j) {
                kb[j]     = ((m2.x >> (8 * j)) & 0xFFu) != 0u;
                kb[4 + j] = ((m2.y >> (8 * j)) & 0xFFu) != 0u;
            }
        } else if (fm == 2) {          // bf16 halves
            uint4 m4 = *((const uint4*)mask + t);
            kb[0] = (m4.x & 0xFFFFu) != 0u; kb[1] = (m4.x >> 16) != 0u;
            kb[2] = (m4.y & 0xFFFFu) != 0u; kb[3] = (m4.y >> 16) != 0u;
            kb[4] = (m4.z & 0xFFFFu) != 0u; kb[5] = (m4.z >> 16) != 0u;
            kb[6] = (m4.w & 0xFFFFu) != 0u; kb[7] = (m4.w >> 16) != 0u;
        } else {                       // int32 {0,1} or fp32 {0,1.0f}: 32-bit words
            const uint4* mp = (const uint4*)mask + (size_t)t * 2;
            uint4 a = mp[0], b = mp[1];
            kb[0] = a.x != 0u; kb[1] = a.y != 0u; kb[2] = a.z != 0u; kb[3] = a.w != 0u;
            kb[4] = b.x != 0u; kb[5] = b.y != 0u; kb[6] = b.z != 0u; kb[7] = b.w != 0u;
        }
        union { __hip_bfloat16 h[8]; uint4 u; } o;
        #pragma unroll
        for (int j = 0; j < 8; ++j)
            o.h[j] = __float2bfloat16(kb[j] ? wv[j] : 0.0f);
        wm4[t] = o.u;
    }
}

// ---------------------------------------------------------------------------
// Kernel 2: m97-style bf16 GEMM, C[M,N] = A[M,K] * B[N,K]^T
// 128x128 block tile, BK=32, 4 waves 2x2, 4x4 MFMA(16x16x32) per wave.
// global_load_lds width=16 staging; LDS layout [row][BK] contiguous.
// Epilogue writes fp32 or bf16 per detected input dtype.
// ---------------------------------------------------------------------------
__global__ void gemm_bt_kernel(const uint16_t* __restrict__ Araw, // x as bf16 bits (valid if fx==0)
                               const uint16_t* __restrict__ Aconv,// xb in ws (valid if fx==1)
                               const uint16_t* __restrict__ B,    // wm bf16 bits [N,K]
                               void* __restrict__ Cout,
                               const int* __restrict__ flags) {
    __shared__ uint16_t sA[BM * BK];   // 8 KiB
    __shared__ uint16_t sB[BN * BK];   // 8 KiB

    const int fx = flags[0];
    const uint16_t* A = fx ? Aconv : Araw;

    const int m0   = blockIdx.y * BM;
    const int n0   = blockIdx.x * BN;
    const int tid  = threadIdx.x;
    const int lane = tid & 63;
    const int wave = tid >> 6;        // 0..3
    const int wm   = (wave >> 1) * 64;
    const int wn   = (wave & 1) * 64;

    f32x4 acc[4][4] = {};

    const char* Abase = (const char*)(A + (size_t)m0 * KDIM);
    const char* Bbase = (const char*)(B + (size_t)n0 * KDIM);
    char* sAb = (char*)sA;
    char* sBb = (char*)sB;

    const int fr = lane & 15;          // fragment row within 16
    const int fk = (lane >> 4) * 8;    // fragment k offset (elements)

    for (int kt = 0; kt < KDIM / BK; ++kt) {
        const int k0 = kt * BK;
        __syncthreads();   // previous iteration's LDS reads complete
        #pragma unroll
        for (int c = 0; c < 2; ++c) {
            const int e   = (wave * 2 + c) * 64 + lane;  // 16-B element index
            const int row = e >> 2;                      // 4 lanes per 64-B row
            const int cb  = (e & 3) * 16;                // byte offset within row
            __builtin_amdgcn_global_load_lds(
                (__attribute__((address_space(1))) void*)(Abase + (size_t)row * (KDIM * 2) + (size_t)k0 * 2 + cb),
                (__attribute__((address_space(3))) void*)(sAb + (wave * 2 + c) * 1024),
                16, 0, 0);
            __builtin_amdgcn_global_load_lds(
                (__attribute__((address_space(1))) void*)(Bbase + (size_t)row * (KDIM * 2) + (size_t)k0 * 2 + cb),
                (__attribute__((address_space(3))) void*)(sBb + (wave * 2 + c) * 1024),
                16, 0, 0);
        }
        __syncthreads();   // staging visible to all waves

        bf16x8 a[4], b[4];
        #pragma unroll
        for (int i = 0; i < 4; ++i)
            a[i] = *(const bf16x8*)(sA + (wm + i * 16 + fr) * BK + fk);
        #pragma unroll
        for (int i = 0; i < 4; ++i)
            b[i] = *(const bf16x8*)(sB + (wn + i * 16 + fr) * BK + fk);

        #pragma unroll
        for (int mi = 0; mi < 4; ++mi)
            #pragma unroll
            for (int ni = 0; ni < 4; ++ni)
                acc[mi][ni] = __builtin_amdgcn_mfma_f32_16x16x32_bf16(
                    a[mi], b[ni], acc[mi][ni], 0, 0, 0);
    }

    // Epilogue: D mapping col = lane&15, row = (lane>>4)*4 + reg
    const int cn = lane & 15;
    const int rq = lane >> 4;
    if (fx) {
        float* C = (float*)Cout;
        #pragma unroll
        for (int mi = 0; mi < 4; ++mi)
            #pragma unroll
            for (int ni = 0; ni < 4; ++ni)
                #pragma unroll
                for (int r = 0; r < 4; ++r) {
                    const int gm = m0 + wm + mi * 16 + rq * 4 + r;
                    const int gn = n0 + wn + ni * 16 + cn;
                    C[(size_t)gm * NDIM + gn] = acc[mi][ni][r];
                }
    } else {
        __hip_bfloat16* C = (__hip_bfloat16*)Cout;
        #pragma unroll
        for (int mi = 0; mi < 4; ++mi)
            #pragma unroll
            for (int ni = 0; ni < 4; ++ni)
                #pragma unroll
                for (int r = 0; r < 4; ++r) {
                    const int gm = m0 + wm + mi * 16 + rq * 4 + r;
                    const int gn = n0 + wn + ni * 16 + cn;
                    C[(size_t)gm * NDIM + gn] = __float2bfloat16(acc[mi][ni][r]);
                }
    }
}

extern "C" void kernel_launch(void* const* d_in, const int* in_sizes, int n_in,
                              void* d_out, int out_size, void* d_ws, size_t ws_size,
                              hipStream_t stream) {
    const void* x    = d_in[0];   // [8192,4096] fp32 (or bf16) — detected on device
    const void* w    = d_in[1];   // [4096,4096] fp32 (or bf16)
    const void* mask = d_in[2];   // [4096,4096] bool — width detected on device

    // ws layout: flags (256 B) | wm bf16 (32 MiB) | xb bf16 (64 MiB)
    int*      flags = (int*)d_ws;
    uint16_t* wm    = (uint16_t*)((char*)d_ws + 256);
    uint16_t* xb    = (uint16_t*)((char*)d_ws + 256 + (size_t)NDIM * KDIM * 2);

    detect_kernel<<<1, 256, 0, stream>>>((const uint32_t*)x, (const uint32_t*)w,
                                         (const uint32_t*)mask, flags);

    // 16384 blocks for x-conv + 8192 blocks for w*mask
    prep_kernel<<<16384 + 8192, 256, 0, stream>>>(x, w, mask, flags,
                                                  (uint4*)xb, (uint4*)wm);

    dim3 grid(NDIM / BN, BATCH / BM);
    gemm_bt_kernel<<<grid, 256, 0, stream>>>((const uint16_t*)x, xb, wm, d_out, flags);
}

// Round 3
// 611.693 us; speedup vs baseline: 1.0157x; 1.0157x over previous
//
#include <hip/hip_runtime.h>
#include <hip/hip_bf16.h>
#include <stdint.h>

#define BATCH 8192
#define KDIM  4096   // IN_FEATURES
#define NDIM  4096   // OUT_FEATURES

#define BM 128
#define BN 128
#define BK 32

typedef __bf16 bf16x8 __attribute__((ext_vector_type(8)));
typedef float  f32x4  __attribute__((ext_vector_type(4)));

__device__ inline float bf2f(uint32_t h) {
    union { uint32_t u; float f; } c; c.u = h << 16; return c.f;
}
__device__ inline uint32_t pk2(float a, float b) {
    union { __hip_bfloat16 h[2]; uint32_t u; } o;
    o.h[0] = __float2bfloat16(a); o.h[1] = __float2bfloat16(b);
    return o.u;
}

// ---------------------------------------------------------------------------
// Kernel 0: detect dtypes device-side (graph-safe, deterministic).
// flags[0]: 1 if x is fp32, 0 if bf16
// flags[1]: 1 if w is fp32, 0 if bf16
// flags[2]: mask enc: 0=int32{0,1}, 1=uint8 bytes, 2=bf16 halves, 3=fp32 {0,1.0f}
// (bf16 exponent-field statistics on the low half of each word: N(0,1) bf16
//  concentrates in [0x70,0x86] ~100%; fp32 mantissa bits are uniform ~9%.)
// ---------------------------------------------------------------------------
__global__ void detect_kernel(const uint32_t* __restrict__ x,
                              const uint32_t* __restrict__ w,
                              const uint32_t* __restrict__ m,
                              int* __restrict__ flags) {
    __shared__ int cx, cw, all01, allf32, anybf16;
    if (threadIdx.x == 0) { cx = 0; cw = 0; all01 = 1; allf32 = 1; anybf16 = 0; }
    __syncthreads();
    int lcx = 0, lcw = 0, la01 = 1, laf = 1, lab = 0;
    #pragma unroll
    for (int jj = 0; jj < 16; ++jj) {
        int i = jj * 256 + threadIdx.x;
        uint32_t vx = x[i], vw = w[i], vm = m[i];
        uint32_t ex = (vx >> 7) & 0xFFu; if (ex >= 0x70u && ex <= 0x86u) lcx++;
        uint32_t ew = (vw >> 7) & 0xFFu; if (ew >= 0x70u && ew <= 0x86u) lcw++;
        if (vm > 1u) la01 = 0;
        if (vm != 0u && vm != 0x3F800000u) laf = 0;
        if ((vm & 0xFFFFu) == 0x3F80u || (vm >> 16) == 0x3F80u) lab = 1;
    }
    atomicAdd(&cx, lcx); atomicAdd(&cw, lcw);
    if (!la01) atomicAnd(&all01, 0);
    if (!laf)  atomicAnd(&allf32, 0);
    if (lab)   atomicOr(&anybf16, 1);
    __syncthreads();
    if (threadIdx.x == 0) {
        flags[0] = (cx < 2048) ? 1 : 0;
        flags[1] = (cw < 2048) ? 1 : 0;
        int f;
        if (all01)        f = 0;
        else if (allf32)  f = 3;
        else if (anybf16) f = 2;
        else              f = 1;
        flags[2] = f;
    }
}

// ---------------------------------------------------------------------------
// Kernel 1: x fp32 -> bf16. One float4 (16 B) load, one uint2 (8 B) store per
// thread, lane-contiguous (coalesced at 1 KiB/wave per instruction).
// 8192*4096/4 = 8.39M threads.
// ---------------------------------------------------------------------------
__global__ void xconv_kernel(const float4* __restrict__ xf,
                             uint2* __restrict__ xb2,
                             const int* __restrict__ flags) {
    if (flags[0] == 0) return;             // x already bf16; GEMM reads it directly
    const int t = blockIdx.x * 256 + threadIdx.x;
    float4 a = xf[t];
    uint2 o; o.x = pk2(a.x, a.y); o.y = pk2(a.z, a.w);
    xb2[t] = o;
}

// ---------------------------------------------------------------------------
// Kernel 2: wm = bf16(w * mask). 4 elements per thread, lane-contiguous:
// w: one float4 (fp32) or uint2 (bf16); mask: uint4 / uint / uint2 per enc.
// 4096*4096/4 = 4.19M threads.
// ---------------------------------------------------------------------------
__global__ void wmask_kernel(const void* __restrict__ w,
                             const void* __restrict__ mask,
                             const int*  __restrict__ flags,
                             uint2* __restrict__ wm2) {
    const int fw = flags[1], fm = flags[2];
    const int t = blockIdx.x * 256 + threadIdx.x;
    float wv[4];
    if (fw) {
        float4 a = ((const float4*)w)[t];
        wv[0] = a.x; wv[1] = a.y; wv[2] = a.z; wv[3] = a.w;
    } else {
        uint2 wb = ((const uint2*)w)[t];
        wv[0] = bf2f(wb.x & 0xFFFFu); wv[1] = bf2f(wb.x >> 16);
        wv[2] = bf2f(wb.y & 0xFFFFu); wv[3] = bf2f(wb.y >> 16);
    }
    int kb[4];
    if (fm == 1) {                       // uint8 bool bytes: 4 B per thread
        uint32_t m1 = ((const uint32_t*)mask)[t];
        kb[0] = (m1 & 0xFFu) != 0u;         kb[1] = ((m1 >> 8) & 0xFFu) != 0u;
        kb[2] = ((m1 >> 16) & 0xFFu) != 0u; kb[3] = (m1 >> 24) != 0u;
    } else if (fm == 2) {                // bf16 halves: 8 B per thread
        uint2 m2 = ((const uint2*)mask)[t];
        kb[0] = (m2.x & 0xFFFFu) != 0u; kb[1] = (m2.x >> 16) != 0u;
        kb[2] = (m2.y & 0xFFFFu) != 0u; kb[3] = (m2.y >> 16) != 0u;
    } else {                             // int32 {0,1} or fp32 {0,1.0f}: 16 B
        uint4 m4 = ((const uint4*)mask)[t];
        kb[0] = m4.x != 0u; kb[1] = m4.y != 0u; kb[2] = m4.z != 0u; kb[3] = m4.w != 0u;
    }
    uint2 o;
    o.x = pk2(kb[0] ? wv[0] : 0.0f, kb[1] ? wv[1] : 0.0f);
    o.y = pk2(kb[2] ? wv[2] : 0.0f, kb[3] ? wv[3] : 0.0f);
    wm2[t] = o;
}

// ---------------------------------------------------------------------------
// Kernel 3: m97-style bf16 GEMM, C[M,N] = A[M,K] * B[N,K]^T
// 128x128 block tile, BK=32, 4 waves 2x2, 4x4 MFMA(16x16x32) per wave.
// global_load_lds width=16 staging; LDS layout [row][BK] contiguous.
// Epilogue writes fp32 or bf16 per detected input dtype.
// ---------------------------------------------------------------------------
__global__ void gemm_bt_kernel(const uint16_t* __restrict__ Araw, // x bf16 bits (if fx==0)
                               const uint16_t* __restrict__ Aconv,// xb in ws (if fx==1)
                               const uint16_t* __restrict__ B,    // wm bf16 bits [N,K]
                               void* __restrict__ Cout,
                               const int* __restrict__ flags) {
    __shared__ uint16_t sA[BM * BK];   // 8 KiB
    __shared__ uint16_t sB[BN * BK];   // 8 KiB

    const int fx = flags[0];
    const uint16_t* A = fx ? Aconv : Araw;

    const int m0   = blockIdx.y * BM;
    const int n0   = blockIdx.x * BN;
    const int tid  = threadIdx.x;
    const int lane = tid & 63;
    const int wave = tid >> 6;        // 0..3
    const int wm   = (wave >> 1) * 64;
    const int wn   = (wave & 1) * 64;

    f32x4 acc[4][4] = {};

    const char* Abase = (const char*)(A + (size_t)m0 * KDIM);
    const char* Bbase = (const char*)(B + (size_t)n0 * KDIM);
    char* sAb = (char*)sA;
    char* sBb = (char*)sB;

    const int fr = lane & 15;          // fragment row within 16
    const int fk = (lane >> 4) * 8;    // fragment k offset (elements)

    for (int kt = 0; kt < KDIM / BK; ++kt) {
        const int k0 = kt * BK;
        __syncthreads();   // previous iteration's LDS reads complete
        #pragma unroll
        for (int c = 0; c < 2; ++c) {
            const int e   = (wave * 2 + c) * 64 + lane;  // 16-B element index
            const int row = e >> 2;                      // 4 lanes per 64-B row
            const int cb  = (e & 3) * 16;                // byte offset within row
            __builtin_amdgcn_global_load_lds(
                (__attribute__((address_space(1))) void*)(Abase + (size_t)row * (KDIM * 2) + (size_t)k0 * 2 + cb),
                (__attribute__((address_space(3))) void*)(sAb + (wave * 2 + c) * 1024),
                16, 0, 0);
            __builtin_amdgcn_global_load_lds(
                (__attribute__((address_space(1))) void*)(Bbase + (size_t)row * (KDIM * 2) + (size_t)k0 * 2 + cb),
                (__attribute__((address_space(3))) void*)(sBb + (wave * 2 + c) * 1024),
                16, 0, 0);
        }
        __syncthreads();   // staging visible to all waves

        bf16x8 a[4], b[4];
        #pragma unroll
        for (int i = 0; i < 4; ++i)
            a[i] = *(const bf16x8*)(sA + (wm + i * 16 + fr) * BK + fk);
        #pragma unroll
        for (int i = 0; i < 4; ++i)
            b[i] = *(const bf16x8*)(sB + (wn + i * 16 + fr) * BK + fk);

        #pragma unroll
        for (int mi = 0; mi < 4; ++mi)
            #pragma unroll
            for (int ni = 0; ni < 4; ++ni)
                acc[mi][ni] = __builtin_amdgcn_mfma_f32_16x16x32_bf16(
                    a[mi], b[ni], acc[mi][ni], 0, 0, 0);
    }

    // Epilogue: D mapping col = lane&15, row = (lane>>4)*4 + reg
    const int cn = lane & 15;
    const int rq = lane >> 4;
    if (fx) {
        float* C = (float*)Cout;
        #pragma unroll
        for (int mi = 0; mi < 4; ++mi)
            #pragma unroll
            for (int ni = 0; ni < 4; ++ni)
                #pragma unroll
                for (int r = 0; r < 4; ++r) {
                    const int gm = m0 + wm + mi * 16 + rq * 4 + r;
                    const int gn = n0 + wn + ni * 16 + cn;
                    C[(size_t)gm * NDIM + gn] = acc[mi][ni][r];
                }
    } else {
        __hip_bfloat16* C = (__hip_bfloat16*)Cout;
        #pragma unroll
        for (int mi = 0; mi < 4; ++mi)
            #pragma unroll
            for (int ni = 0; ni < 4; ++ni)
                #pragma unroll
                for (int r = 0; r < 4; ++r) {
                    const int gm = m0 + wm + mi * 16 + rq * 4 + r;
                    const int gn = n0 + wn + ni * 16 + cn;
                    C[(size_t)gm * NDIM + gn] = __float2bfloat16(acc[mi][ni][r]);
                }
    }
}

extern "C" void kernel_launch(void* const* d_in, const int* in_sizes, int n_in,
                              void* d_out, int out_size, void* d_ws, size_t ws_size,
                              hipStream_t stream) {
    const void* x    = d_in[0];   // [8192,4096] fp32 (or bf16) — detected on device
    const void* w    = d_in[1];   // [4096,4096] fp32 (or bf16)
    const void* mask = d_in[2];   // [4096,4096] bool — width detected on device

    // ws layout: flags (256 B) | wm bf16 (32 MiB) | xb bf16 (64 MiB)
    int*      flags = (int*)d_ws;
    uint16_t* wm    = (uint16_t*)((char*)d_ws + 256);
    uint16_t* xb    = (uint16_t*)((char*)d_ws + 256 + (size_t)NDIM * KDIM * 2);

    detect_kernel<<<1, 256, 0, stream>>>((const uint32_t*)x, (const uint32_t*)w,
                                         (const uint32_t*)mask, flags);

    // x conversion: 8192*4096/4 threads, 16 B load / 8 B store per thread
    xconv_kernel<<<(BATCH * KDIM / 4) / 256, 256, 0, stream>>>(
        (const float4*)x, (uint2*)xb, flags);

    // w*mask: 4096*4096/4 threads
    wmask_kernel<<<(NDIM * KDIM / 4) / 256, 256, 0, stream>>>(
        w, mask, flags, (uint2*)wm);

    dim3 grid(NDIM / BN, BATCH / BM);
    gemm_bt_kernel<<<grid, 256, 0, stream>>>((const uint16_t*)x, xb, wm, d_out, flags);
}